// Round 11
// baseline (193.190 us; speedup 1.0000x reference)
//
#include <hip/hip_runtime.h>

// Problem constants (from reference)
#define B_    32
#define C_    256
#define H_    56
#define W_    56
#define HW    (H_ * W_)          // 3136
#define HW4   (HW / 4)           // 784 f32x4 per channel plane
#define NSEL  8
#define NTOT  (B_ * C_ * HW)     // 25,690,112 elements
#define NTOT4 (NTOT / 4)         // 6,422,528 f32x4
#define NSELTOT4 (B_ * NSEL * HW4)  // 200,704 f32x4 in selected slice

#define RED_BLOCKS 256
#define TPB        256

typedef float f32x4 __attribute__((ext_vector_type(4)));

// ws layout (floats): [0..256) partial mins | [256..512) partial maxes
__global__ __launch_bounds__(TPB)
void k_minmax(const float* __restrict__ in, const int* __restrict__ sel,
              float* __restrict__ ws) {
    __shared__ float smn[TPB], smx[TPB];
    __shared__ int ssel[NSEL];
    if (threadIdx.x < NSEL) ssel[threadIdx.x] = sel[threadIdx.x];
    __syncthreads();

    float mn = INFINITY, mx = -INFINITY;
    const f32x4* in4 = reinterpret_cast<const f32x4*>(in);
    for (int i = blockIdx.x * TPB + threadIdx.x; i < NSELTOT4;
         i += RED_BLOCKS * TPB) {
        int pos = i % HW4;
        int t   = i / HW4;
        int j   = t % NSEL;
        int b   = t / NSEL;
        f32x4 v = in4[(b * C_ + ssel[j]) * HW4 + pos];
        mn = fminf(mn, fminf(fminf(v.x, v.y), fminf(v.z, v.w)));
        mx = fmaxf(mx, fmaxf(fmaxf(v.x, v.y), fmaxf(v.z, v.w)));
    }
    smn[threadIdx.x] = mn;
    smx[threadIdx.x] = mx;
    __syncthreads();
    for (int s = TPB / 2; s > 0; s >>= 1) {
        if (threadIdx.x < s) {
            smn[threadIdx.x] = fminf(smn[threadIdx.x], smn[threadIdx.x + s]);
            smx[threadIdx.x] = fmaxf(smx[threadIdx.x], smx[threadIdx.x + s]);
        }
        __syncthreads();
    }
    if (threadIdx.x == 0) {
        ws[blockIdx.x]              = smn[0];
        ws[RED_BLOCKS + blockIdx.x] = smx[0];
    }
}

__device__ __forceinline__ float qmix(float x, float mn,
                                      float sc2, float sc4, float sc8,
                                      float sw0, float sw1, float sw2) {
    float d = x - mn;
    // jnp.round == round-half-to-even == rintf (default rounding mode)
    float q2 = fminf(fmaxf(rintf(d / sc2), 0.0f), 3.0f);
    float q4 = fminf(fmaxf(rintf(d / sc4), 0.0f), 15.0f);
    float q8 = fminf(fmaxf(rintf(d / sc8), 0.0f), 255.0f);
    float o2 = q2 * sc2 + mn;
    float o4 = q4 * sc4 + mn;
    float o8 = q8 * sc8 + mn;
    return o2 * sw0 + o4 * sw1 + o8 * sw2;  // same left-to-right order as ref
}

// Every block redundantly reduces the 256 partials (2 KB, L2-hot; kernel
// boundary guarantees visibility of ws), computes softmax + flags, then
// streams. A/B vs round 9: ONLY change is plain store instead of
// __builtin_nontemporal_store (nt suspected of killing write BW: 2.5 TB/s
// vs fill's 6.8 TB/s on identical hardware path).
__global__ __launch_bounds__(TPB)
void k_main2(const float* __restrict__ in, const float* __restrict__ beta,
             const int* __restrict__ sel, float* __restrict__ out,
             const float* __restrict__ ws) {
    __shared__ float smn[TPB], smx[TPB];
    __shared__ int flags[C_];
    const int tid = threadIdx.x;

    // final min/max reduce: TPB == RED_BLOCKS, one partial pair per thread
    smn[tid] = ws[tid];
    smx[tid] = ws[RED_BLOCKS + tid];
    __syncthreads();
    for (int s = TPB / 2; s > 0; s >>= 1) {
        if (tid < s) {
            smn[tid] = fminf(smn[tid], smn[tid + s]);
            smx[tid] = fmaxf(smx[tid], smx[tid + s]);
        }
        __syncthreads();
    }
    const float mnf = smn[0];
    const float mxf = smx[0];

    // flag table: TPB == C_ == 256, one channel per thread (sel is L2-hot)
    int f = 0;
    #pragma unroll
    for (int j = 0; j < NSEL; ++j) f |= (sel[j] == tid) ? 1 : 0;
    flags[tid] = f;
    __syncthreads();

    // softmax of beta — all threads redundantly, registers only
    const float b0 = beta[0], b1 = beta[1], b2 = beta[2];
    const float bm = fmaxf(b0, fmaxf(b1, b2));
    const float e0 = expf(b0 - bm), e1 = expf(b1 - bm), e2 = expf(b2 - bm);
    const float inv = 1.0f / (e0 + e1 + e2);
    const float sw0 = e0 * inv, sw1 = e1 * inv, sw2 = e2 * inv;

    const float range = mxf - mnf;
    const float sc2 = range / 3.0f;
    const float sc4 = range / 15.0f;
    const float sc8 = range / 255.0f;

    // returned scale = final loop iteration's (bit=8)
    if (blockIdx.x == 0 && tid == 0) out[NTOT] = sc8;

    // streaming copy / quant-mix over the full tensor
    const f32x4* in4 = reinterpret_cast<const f32x4*>(in);
    f32x4* out4 = reinterpret_cast<f32x4*>(out);
    for (int i = blockIdx.x * TPB + tid; i < NTOT4;
         i += gridDim.x * TPB) {
        f32x4 v = in4[i];
        int c = (i / HW4) % C_;  // f32x4 fully inside one channel plane
        if (flags[c]) {
            v.x = qmix(v.x, mnf, sc2, sc4, sc8, sw0, sw1, sw2);
            v.y = qmix(v.y, mnf, sc2, sc4, sc8, sw0, sw1, sw2);
            v.z = qmix(v.z, mnf, sc2, sc4, sc8, sw0, sw1, sw2);
            v.w = qmix(v.w, mnf, sc2, sc4, sc8, sw0, sw1, sw2);
        }
        out4[i] = v;  // plain store (A/B: was nontemporal in round 9)
    }
}

extern "C" void kernel_launch(void* const* d_in, const int* in_sizes, int n_in,
                              void* d_out, int out_size, void* d_ws, size_t ws_size,
                              hipStream_t stream) {
    const float* input = (const float*)d_in[0];
    const float* beta  = (const float*)d_in[1];
    const int*   sel   = (const int*)d_in[2];
    float* out = (float*)d_out;
    float* ws  = (float*)d_ws;

    // 1) partial min/max over the selected slice
    k_minmax<<<RED_BLOCKS, TPB, 0, stream>>>(input, sel, ws);
    // 2) redundant finish + streaming quant-mix (kernel boundary = sync)
    k_main2<<<4096, TPB, 0, stream>>>(input, beta, sel, out, ws);
}